// Round 2
// baseline (966.962 us; speedup 1.0000x reference)
//
#include <hip/hip_runtime.h>
#include <cstdint>

#define Bz 64
#define Vz 64
#define Hz 512
#define Oz 64
#define Nz 1024
#define Wdz 64
#define Rz 4
#define XIz 471
#define EPSf 1e-06f

__device__ __forceinline__ float sigm(float x){ return 1.0f/(1.0f+expf(-x)); }
__device__ __forceinline__ float oneplusf(float x){
    // 1 + softplus(x), numerically stable like jax.nn.softplus
    return 1.0f + fmaxf(x,0.0f) + log1pf(expf(-fabsf(x)));
}

// block-wide reduce over blockDim.x (multiple of 64) threads; scratch >= blockDim.x/64 floats
__device__ __forceinline__ float block_reduce(float v, float* s, bool mx){
    int lane = threadIdx.x & 63, wid = threadIdx.x >> 6, nw = blockDim.x >> 6;
    #pragma unroll
    for(int o=32;o;o>>=1){ float t=__shfl_xor(v,o); v = mx? fmaxf(v,t) : v+t; }
    __syncthreads();
    if(lane==0) s[wid]=v;
    __syncthreads();
    float r = s[0];
    for(int i=1;i<nw;i++){ float t=s[i]; r = mx? fmaxf(r,t) : r+t; }
    return r;
}

// ---------------- K1: LSTM gates  gates[g][b] = sum_k W[g,k]*inp[b,k] + bias -------------
__global__ __launch_bounds__(256) void k_gates(const float* __restrict__ x, const float* __restrict__ rv,
    const float* __restrict__ h0, const float* __restrict__ W_ih, const float* __restrict__ W_hh,
    const float* __restrict__ b_lstm, float* __restrict__ gates){
    __shared__ float inp_s[64][64]; // [k][b]
    __shared__ float w_s[16][64];   // [g][k]
    int t = threadIdx.x; int g0 = blockIdx.x*16;
    int b = t & 63, slot = t >> 6;
    float acc[4] = {0.f,0.f,0.f,0.f};
    for(int kc=0; kc<13; kc++){
        __syncthreads();
        #pragma unroll
        for(int it=0; it<16; it++){
            int e = it*256 + t; int bb = e & 63, kl = e >> 6; int kk = kc*64 + kl;
            float v;
            if (kk < 64)       v = x[bb*64 + kk];
            else if (kk < 320){ int j = kk-64; v = rv[bb*256 + (j&63)*4 + (j>>6)]; }
            else               v = h0[bb*512 + (kk-320)];
            inp_s[kl][bb] = v;
        }
        #pragma unroll
        for(int it=0; it<4; it++){
            int e = it*256 + t; int kl = e & 63, gl = e >> 6; int g = g0 + gl; int kk = kc*64 + kl;
            w_s[gl][kl] = (kk < 320) ? W_ih[g*320 + kk] : W_hh[g*512 + (kk-320)];
        }
        __syncthreads();
        #pragma unroll 8
        for(int k=0;k<64;k++){
            float iv = inp_s[k][b];
            #pragma unroll
            for(int i=0;i<4;i++) acc[i] += w_s[slot*4+i][k]*iv;
        }
    }
    #pragma unroll
    for(int i=0;i<4;i++){
        int g = g0 + slot*4 + i;
        gates[g*64 + b] = acc[i] + b_lstm[g];
    }
}

// ---------------- K1b: h,c ----------------
__global__ __launch_bounds__(256) void k_hc(const float* __restrict__ gates, const float* __restrict__ c0,
    float* __restrict__ h, float* __restrict__ c){
    int gt = blockIdx.x*256 + threadIdx.x;
    int b = gt >> 9, j = gt & 511;
    float gi = gates[j*64+b], gf = gates[(512+j)*64+b], gg = gates[(1024+j)*64+b], go = gates[(1536+j)*64+b];
    float cc = sigm(gf)*c0[b*512+j] + sigm(gi)*tanhf(gg);
    float hh = sigm(go)*tanhf(cc);
    c[b*512+j] = cc; h[b*512+j] = hh;
}

// ---------------- K2: vu = h@W_v, xi = h@W_xi ----------------
__global__ __launch_bounds__(256) void k_vuxi(const float* __restrict__ h, const float* __restrict__ W_v,
    const float* __restrict__ W_xi, float* __restrict__ vu, float* __restrict__ xi){
    __shared__ float h_s[64][64]; // [k][b]
    __shared__ float w_s[64][4];  // [k][oslot]
    int t = threadIdx.x; int b = t & 63, slot = t >> 6;
    int o = blockIdx.x*4 + slot;
    float acc = 0.f;
    for(int kc=0; kc<8; kc++){
        __syncthreads();
        #pragma unroll
        for(int it=0; it<16; it++){
            int e = it*256 + t; int bb = e & 63, kl = e >> 6;
            h_s[kl][bb] = h[bb*512 + kc*64 + kl];
        }
        {
            int kl = t >> 2, os = t & 3; int og = blockIdx.x*4 + os; int kk = kc*64 + kl;
            float v = 0.f;
            if (og < 64) v = W_v[kk*64 + og];
            else if (og < 535) v = W_xi[kk*471 + (og-64)];
            w_s[kl][os] = v;
        }
        __syncthreads();
        #pragma unroll 8
        for(int k=0;k<64;k++) acc += h_s[k][b]*w_s[k][slot];
    }
    if (o < 535){
        if (o < 64) vu[b*64 + o] = acc;
        else        xi[b*480 + (o-64)] = acc;
    }
}

// ---------------- K3: psi,u and content write weight cw ----------------
__global__ __launch_bounds__(1024) void k_content_w(const float* __restrict__ M, const float* __restrict__ xi,
    const float* __restrict__ wr, const float* __restrict__ usage, const float* __restrict__ ww,
    float* __restrict__ u_out, float* __restrict__ cw_ws){
    int b = blockIdx.x, n = threadIdx.x;
    __shared__ float wk_s[64];
    __shared__ float red[16];
    const float* xib = xi + b*480;
    if (n < 64) wk_s[n] = xib[260+n];
    __syncthreads();
    float s2 = 0.f;
    #pragma unroll 8
    for(int w=0;w<64;w++){ float v = wk_s[w]; s2 += v*v; }
    float nwk = sqrtf(s2);
    // psi, u
    float4 wr4 = *(const float4*)&wr[(b*Nz+n)*4];
    float f0 = sigm(xib[453]), f1 = sigm(xib[454]), f2 = sigm(xib[455]), f3 = sigm(xib[456]);
    float psi = (1.f - f0*wr4.x)*(1.f - f1*wr4.y)*(1.f - f2*wr4.z)*(1.f - f3*wr4.w);
    float us = usage[b*Nz+n], w_ = ww[b*Nz+n];
    float u = (us + w_ - us*w_)*psi;
    u_out[b*Nz+n] = u;
    // sim with write key
    const float4* mrow = (const float4*)&M[(size_t)(b*Nz+n)*64];
    float dot = 0.f, nm = 0.f;
    #pragma unroll
    for(int q=0;q<16;q++){
        float4 m = mrow[q];
        dot += m.x*wk_s[q*4+0] + m.y*wk_s[q*4+1] + m.z*wk_s[q*4+2] + m.w*wk_s[q*4+3];
        nm  += m.x*m.x + m.y*m.y + m.z*m.z + m.w*m.w;
    }
    float sim = dot/(sqrtf(nm)*nwk + EPSf);
    float wstr = oneplusf(xib[324]);
    float logit = wstr*sim;
    float mx = block_reduce(logit, red, true);
    float ex = expf(logit - mx);
    float sm = block_reduce(ex, red, false);
    cw_ws[b*Nz+n] = ex/sm;
}

// ---------------- K4: stable argsort + cumprod -> allocation a ----------------
__global__ __launch_bounds__(1024) void k_alloc(const float* __restrict__ u_out, float* __restrict__ a_ws){
    int b = blockIdx.x, n = threadIdx.x;
    __shared__ unsigned long long keys[1024];
    __shared__ float p0[1024], p1[1024];
    float u = u_out[b*Nz+n];
    keys[n] = (((unsigned long long)__float_as_uint(u)) << 32) | (unsigned)n;
    __syncthreads();
    for(int k=2;k<=1024;k<<=1){
        for(int j=k>>1;j>0;j>>=1){
            int ixj = n ^ j;
            if (ixj > n){
                unsigned long long a = keys[n], c = keys[ixj];
                bool up = ((n & k) == 0);
                bool sw = up ? (a > c) : (a < c);
                if (sw){ keys[n] = c; keys[ixj] = a; }
            }
            __syncthreads();
        }
    }
    unsigned long long kk = keys[n];
    float us = __uint_as_float((unsigned)(kk >> 32));
    int idx = (int)(kk & 0xffffffffULL);
    p0[n] = us;
    __syncthreads();
    float* cur = p0; float* nxt = p1;
    for(int off=1; off<1024; off<<=1){
        float v = cur[n];
        if (n >= off) v *= cur[n-off];
        nxt[n] = v;
        __syncthreads();
        float* tmp = cur; cur = nxt; nxt = tmp;
    }
    float excl = (n==0) ? 1.f : cur[n-1];
    a_ws[b*Nz + idx] = (1.f - us)*excl;
}

// ---------------- K5: ww_n and prec_n ----------------
__global__ __launch_bounds__(1024) void k_wwn(const float* __restrict__ a_ws, const float* __restrict__ cw_ws,
    const float* __restrict__ xi, const float* __restrict__ prec_in,
    float* __restrict__ wwn_out, float* __restrict__ precn_out){
    int b = blockIdx.x, n = threadIdx.x;
    __shared__ float red[16];
    const float* xib = xi + b*480;
    float ag = sigm(xib[457]), wg = sigm(xib[458]);
    float wwn = wg*(ag*a_ws[b*Nz+n] + (1.f-ag)*cw_ws[b*Nz+n]);
    wwn_out[b*Nz+n] = wwn;
    float s = block_reduce(wwn, red, false);
    precn_out[b*Nz+n] = (1.f - s)*prec_in[b*Nz+n] + wwn;
}

// ---------------- K6: memory update + row norms ----------------
__global__ __launch_bounds__(256) void k_memup(const float* __restrict__ M, const float* __restrict__ wwn,
    const float* __restrict__ xi, float* __restrict__ Mn_out, float* __restrict__ Mn2_ws){
    int t = threadIdx.x; int w = t & 63; int bn = blockIdx.x*4 + (t >> 6);
    int b = bn >> 10;
    const float* xib = xi + b*480;
    float er = sigm(xib[325+w]);
    float wv = xib[389+w];
    float wn = wwn[bn];
    float m = M[(size_t)bn*64 + w];
    float mn = m*(1.f - wn*er) + wn*wv;
    Mn_out[(size_t)bn*64 + w] = mn;
    float s = mn*mn;
    #pragma unroll
    for(int o=32;o;o>>=1) s += __shfl_xor(s,o);
    if (w == 0) Mn2_ws[bn] = sqrtf(s);
}

// ---------------- K7: L + fwd + bwd fused ----------------
__global__ __launch_bounds__(256) void k7_link(const float* __restrict__ link, const float* __restrict__ wr,
    const float* __restrict__ prec, const float* __restrict__ wwn, float* __restrict__ Lout,
    float* __restrict__ fwd, float* __restrict__ bwd){
    int b = blockIdx.y, n0 = blockIdx.x*64, t = threadIdx.x;
    __shared__ float rowwr[64][4];
    __shared__ float rowwwn[64];
    __shared__ float fs[64][4][4]; // [row][wave][r]
    if (t < 64){
        float4 w4 = *(const float4*)&wr[(b*Nz + n0 + t)*4];
        rowwr[t][0]=w4.x; rowwr[t][1]=w4.y; rowwr[t][2]=w4.z; rowwr[t][3]=w4.w;
        rowwwn[t] = wwn[b*Nz + n0 + t];
    }
    int m0 = 4*t;
    float4 wn4 = *(const float4*)&wwn[b*Nz + m0];
    float4 pm4 = *(const float4*)&prec[b*Nz + m0];
    float cm[4] = {1.f-wn4.x, 1.f-wn4.y, 1.f-wn4.z, 1.f-wn4.w};
    float pm[4] = {pm4.x, pm4.y, pm4.z, pm4.w};
    float wreg[4][4];
    #pragma unroll
    for(int e=0;e<4;e++){
        float4 w4 = *(const float4*)&wr[(b*Nz + m0 + e)*4];
        wreg[e][0]=w4.x; wreg[e][1]=w4.y; wreg[e][2]=w4.z; wreg[e][3]=w4.w;
    }
    float bacc[4][4];
    #pragma unroll
    for(int e=0;e<4;e++){ bacc[e][0]=0.f; bacc[e][1]=0.f; bacc[e][2]=0.f; bacc[e][3]=0.f; }
    __syncthreads();
    int wid = t >> 6;
    for(int i=0;i<64;i++){
        int n = n0 + i;
        float wn = rowwwn[i];
        float w0 = rowwr[i][0], w1 = rowwr[i][1], w2 = rowwr[i][2], w3 = rowwr[i][3];
        float4 lv = ((const float4*)(link + (size_t)(b*Nz + n)*Nz))[t];
        float Le[4];
        Le[0] = (cm[0]-wn)*lv.x + wn*pm[0];
        Le[1] = (cm[1]-wn)*lv.y + wn*pm[1];
        Le[2] = (cm[2]-wn)*lv.z + wn*pm[2];
        Le[3] = (cm[3]-wn)*lv.w + wn*pm[3];
        #pragma unroll
        for(int e=0;e<4;e++) if (m0 + e == n) Le[e] = 0.f;
        ((float4*)(Lout + (size_t)(b*Nz + n)*Nz))[t] = make_float4(Le[0],Le[1],Le[2],Le[3]);
        float f0=0.f,f1=0.f,f2=0.f,f3=0.f;
        #pragma unroll
        for(int e=0;e<4;e++){
            f0 += Le[e]*wreg[e][0]; f1 += Le[e]*wreg[e][1];
            f2 += Le[e]*wreg[e][2]; f3 += Le[e]*wreg[e][3];
            bacc[e][0] += Le[e]*w0; bacc[e][1] += Le[e]*w1;
            bacc[e][2] += Le[e]*w2; bacc[e][3] += Le[e]*w3;
        }
        #pragma unroll
        for(int o=32;o;o>>=1){
            f0 += __shfl_xor(f0,o); f1 += __shfl_xor(f1,o);
            f2 += __shfl_xor(f2,o); f3 += __shfl_xor(f3,o);
        }
        if ((t & 63) == 0){ fs[i][wid][0]=f0; fs[i][wid][1]=f1; fs[i][wid][2]=f2; fs[i][wid][3]=f3; }
    }
    __syncthreads();
    {
        int row = t >> 2, r = t & 3;
        float s = fs[row][0][r] + fs[row][1][r] + fs[row][2][r] + fs[row][3][r];
        fwd[(b*Nz + n0 + row)*4 + r] = s;
    }
    #pragma unroll
    for(int e=0;e<4;e++)
        #pragma unroll
        for(int r=0;r<4;r++)
            atomicAdd(&bwd[(b*Nz + m0 + e)*4 + r], bacc[e][r]);
}

// ---------------- K8: read content weight + wr_n ----------------
__global__ __launch_bounds__(1024) void k_read_w(const float* __restrict__ Mn, const float* __restrict__ Mn2_ws,
    const float* __restrict__ xi, const float* __restrict__ fwd, const float* __restrict__ bwd,
    float* __restrict__ wr_out){
    int b = blockIdx.x, n = threadIdx.x;
    __shared__ float rk_s[4][64];
    __shared__ float rkn_s[4], rstr_s[4], pi_s[3][4];
    __shared__ float red[16];
    const float* xib = xi + b*480;
    if (n < 256) rk_s[n & 3][n >> 2] = xib[n];
    __syncthreads();
    if (n < 4){
        float s = 0.f;
        for(int w=0;w<64;w++){ float v = rk_s[n][w]; s += v*v; }
        rkn_s[n] = sqrtf(s);
        rstr_s[n] = oneplusf(xib[256+n]);
        float m0 = xib[459+n], m1 = xib[463+n], m2 = xib[467+n];
        float mxm = fmaxf(m0, fmaxf(m1, m2));
        float e0 = expf(m0-mxm), e1 = expf(m1-mxm), e2 = expf(m2-mxm);
        float se = e0+e1+e2;
        pi_s[0][n] = e0/se; pi_s[1][n] = e1/se; pi_s[2][n] = e2/se;
    }
    __syncthreads();
    const float4* mrow = (const float4*)&Mn[(size_t)(b*Nz+n)*64];
    float d0=0.f,d1=0.f,d2=0.f,d3=0.f;
    #pragma unroll
    for(int q=0;q<16;q++){
        float4 m = mrow[q];
        d0 += m.x*rk_s[0][q*4+0] + m.y*rk_s[0][q*4+1] + m.z*rk_s[0][q*4+2] + m.w*rk_s[0][q*4+3];
        d1 += m.x*rk_s[1][q*4+0] + m.y*rk_s[1][q*4+1] + m.z*rk_s[1][q*4+2] + m.w*rk_s[1][q*4+3];
        d2 += m.x*rk_s[2][q*4+0] + m.y*rk_s[2][q*4+1] + m.z*rk_s[2][q*4+2] + m.w*rk_s[2][q*4+3];
        d3 += m.x*rk_s[3][q*4+0] + m.y*rk_s[3][q*4+1] + m.z*rk_s[3][q*4+2] + m.w*rk_s[3][q*4+3];
    }
    float mn2 = Mn2_ws[b*Nz+n];
    float sim[4] = { d0/(mn2*rkn_s[0]+EPSf), d1/(mn2*rkn_s[1]+EPSf),
                     d2/(mn2*rkn_s[2]+EPSf), d3/(mn2*rkn_s[3]+EPSf) };
    float cr[4];
    for(int r=0;r<4;r++){
        float logit = rstr_s[r]*sim[r];
        float mx = block_reduce(logit, red, true);
        float e = expf(logit - mx);
        float sm = block_reduce(e, red, false);
        cr[r] = e/sm;
    }
    float4 f4 = *(const float4*)&fwd[(b*Nz+n)*4];
    float4 b4 = *(const float4*)&bwd[(b*Nz+n)*4];
    float o0 = pi_s[0][0]*b4.x + pi_s[1][0]*cr[0] + pi_s[2][0]*f4.x;
    float o1 = pi_s[0][1]*b4.y + pi_s[1][1]*cr[1] + pi_s[2][1]*f4.y;
    float o2 = pi_s[0][2]*b4.z + pi_s[1][2]*cr[2] + pi_s[2][2]*f4.z;
    float o3 = pi_s[0][3]*b4.w + pi_s[1][3]*cr[3] + pi_s[2][3]*f4.w;
    *(float4*)&wr_out[(b*Nz+n)*4] = make_float4(o0,o1,o2,o3);
}

// ---------------- K9: rv_n = einsum('bnw,bnr->bwr') ----------------
__global__ __launch_bounds__(256) void k_rv(const float* __restrict__ Mn, const float* __restrict__ wrn,
    float* __restrict__ rv_out){
    int b = blockIdx.y, chunk = blockIdx.x;
    int t = threadIdx.x; int w = t & 63, r = t >> 6;
    float acc = 0.f;
    #pragma unroll 4
    for(int i=0;i<128;i++){
        int n = chunk*128 + i;
        acc += Mn[(size_t)(b*Nz+n)*64 + w] * wrn[(b*Nz+n)*4 + r];
    }
    atomicAdd(&rv_out[b*256 + w*4 + r], acc);
}

// ---------------- K10: y = vu + read_flat_n @ W_read ----------------
__global__ __launch_bounds__(256) void k_y(const float* __restrict__ vu, const float* __restrict__ rv,
    const float* __restrict__ W_read, float* __restrict__ y){
    int gt = blockIdx.x*256 + threadIdx.x;
    int b = gt >> 6, o = gt & 63;
    float acc = vu[b*64 + o];
    #pragma unroll 4
    for(int k=0;k<256;k++){
        int r = k >> 6, w = k & 63;
        acc += rv[b*256 + w*4 + r] * W_read[k*64 + o];
    }
    y[b*64 + o] = acc;
}

extern "C" void kernel_launch(void* const* d_in, const int* in_sizes, int n_in,
                              void* d_out, int out_size, void* d_ws, size_t ws_size,
                              hipStream_t stream) {
    const float* x     = (const float*)d_in[0];
    const float* h0    = (const float*)d_in[1];
    const float* c0    = (const float*)d_in[2];
    const float* W_ih  = (const float*)d_in[3];
    const float* W_hh  = (const float*)d_in[4];
    const float* b_l   = (const float*)d_in[5];
    const float* W_v   = (const float*)d_in[6];
    const float* W_xi  = (const float*)d_in[7];
    const float* W_rd  = (const float*)d_in[8];
    const float* rv    = (const float*)d_in[9];
    const float* M     = (const float*)d_in[10];
    const float* usage = (const float*)d_in[11];
    const float* prec  = (const float*)d_in[12];
    const float* link  = (const float*)d_in[13];
    const float* wr    = (const float*)d_in[14];
    const float* ww    = (const float*)d_in[15];

    float* out = (float*)d_out;
    float* o_y    = out + 0;
    float* o_h    = out + 4096;
    float* o_c    = out + 36864;
    float* o_rv   = out + 69632;
    float* o_Mn   = out + 86016;
    float* o_u    = out + 4280320;
    float* o_prec = out + 4345856;
    float* o_L    = out + 4411392;
    float* o_wrn  = out + 71520256;
    float* o_wwn  = out + 71782400;

    float* ws    = (float*)d_ws;
    float* gates = ws;                 // 131072
    float* xi    = gates + 131072;     // 64*480
    float* vu    = xi + 30720;         // 4096
    float* cw    = vu + 4096;          // 65536
    float* a     = cw + 65536;         // 65536
    float* Mn2   = a + 65536;          // 65536
    float* fwd   = Mn2 + 65536;        // 262144
    float* bwd   = fwd + 262144;       // 262144

    hipMemsetAsync(bwd, 0, 262144*sizeof(float), stream);
    hipMemsetAsync(o_rv, 0, 16384*sizeof(float), stream);

    k_gates<<<128, 256, 0, stream>>>(x, rv, h0, W_ih, W_hh, b_l, gates);
    k_hc<<<128, 256, 0, stream>>>(gates, c0, o_h, o_c);
    k_vuxi<<<134, 256, 0, stream>>>(o_h, W_v, W_xi, vu, xi);
    k_content_w<<<64, 1024, 0, stream>>>(M, xi, wr, usage, ww, o_u, cw);
    k_alloc<<<64, 1024, 0, stream>>>(o_u, a);
    k_wwn<<<64, 1024, 0, stream>>>(a, cw, xi, prec, o_wwn, o_prec);
    k_memup<<<16384, 256, 0, stream>>>(M, o_wwn, xi, o_Mn, Mn2);
    k7_link<<<dim3(16,64), 256, 0, stream>>>(link, wr, prec, o_wwn, o_L, fwd, bwd);
    k_read_w<<<64, 1024, 0, stream>>>(o_Mn, Mn2, xi, fwd, bwd, o_wrn);
    k_rv<<<dim3(8,64), 256, 0, stream>>>(o_Mn, o_wrn, o_rv);
    k_y<<<16, 256, 0, stream>>>(vu, o_rv, W_rd, o_y);
}

// Round 3
// 715.766 us; speedup vs baseline: 1.3509x; 1.3509x over previous
//
#include <hip/hip_runtime.h>
#include <cstdint>

#define Bz 64
#define Nz 1024
#define EPSf 1e-06f

__device__ __forceinline__ float sigm(float x){ return 1.0f/(1.0f+expf(-x)); }
__device__ __forceinline__ float oneplusf(float x){
    return 1.0f + fmaxf(x,0.0f) + log1pf(expf(-fabsf(x)));
}

// block-wide reduce; scratch >= blockDim.x/64 floats
__device__ __forceinline__ float block_reduce(float v, float* s, bool mx){
    int lane = threadIdx.x & 63, wid = threadIdx.x >> 6, nw = blockDim.x >> 6;
    #pragma unroll
    for(int o=32;o;o>>=1){ float t=__shfl_xor(v,o); v = mx? fmaxf(v,t) : v+t; }
    __syncthreads();
    if(lane==0) s[wid]=v;
    __syncthreads();
    float r = s[0];
    for(int i=1;i<nw;i++){ float t=s[i]; r = mx? fmaxf(r,t) : r+t; }
    return r;
}

// ---------------- K1: LSTM gates ----------------
__global__ __launch_bounds__(256) void k_gates(const float* __restrict__ x, const float* __restrict__ rv,
    const float* __restrict__ h0, const float* __restrict__ W_ih, const float* __restrict__ W_hh,
    const float* __restrict__ b_lstm, float* __restrict__ gates){
    __shared__ float inp_s[64][64];
    __shared__ float w_s[16][64];
    int t = threadIdx.x; int g0 = blockIdx.x*16;
    int b = t & 63, slot = t >> 6;
    float acc[4] = {0.f,0.f,0.f,0.f};
    for(int kc=0; kc<13; kc++){
        __syncthreads();
        #pragma unroll
        for(int it=0; it<16; it++){
            int e = it*256 + t; int bb = e & 63, kl = e >> 6; int kk = kc*64 + kl;
            float v;
            if (kk < 64)       v = x[bb*64 + kk];
            else if (kk < 320){ int j = kk-64; v = rv[bb*256 + (j&63)*4 + (j>>6)]; }
            else               v = h0[bb*512 + (kk-320)];
            inp_s[kl][bb] = v;
        }
        #pragma unroll
        for(int it=0; it<4; it++){
            int e = it*256 + t; int kl = e & 63, gl = e >> 6; int g = g0 + gl; int kk = kc*64 + kl;
            w_s[gl][kl] = (kk < 320) ? W_ih[g*320 + kk] : W_hh[g*512 + (kk-320)];
        }
        __syncthreads();
        #pragma unroll 8
        for(int k=0;k<64;k++){
            float iv = inp_s[k][b];
            #pragma unroll
            for(int i=0;i<4;i++) acc[i] += w_s[slot*4+i][k]*iv;
        }
    }
    #pragma unroll
    for(int i=0;i<4;i++){
        int g = g0 + slot*4 + i;
        gates[g*64 + b] = acc[i] + b_lstm[g];
    }
}

// ---------------- K1b: h,c ----------------
__global__ __launch_bounds__(256) void k_hc(const float* __restrict__ gates, const float* __restrict__ c0,
    float* __restrict__ h, float* __restrict__ c){
    int gt = blockIdx.x*256 + threadIdx.x;
    int b = gt >> 9, j = gt & 511;
    float gi = gates[j*64+b], gf = gates[(512+j)*64+b], gg = gates[(1024+j)*64+b], go = gates[(1536+j)*64+b];
    float cc = sigm(gf)*c0[b*512+j] + sigm(gi)*tanhf(gg);
    float hh = sigm(go)*tanhf(cc);
    c[b*512+j] = cc; h[b*512+j] = hh;
}

// ---------------- K2: vu, xi ----------------
__global__ __launch_bounds__(256) void k_vuxi(const float* __restrict__ h, const float* __restrict__ W_v,
    const float* __restrict__ W_xi, float* __restrict__ vu, float* __restrict__ xi){
    __shared__ float h_s[64][64];
    __shared__ float w_s[64][4];
    int t = threadIdx.x; int b = t & 63, slot = t >> 6;
    int o = blockIdx.x*4 + slot;
    float acc = 0.f;
    for(int kc=0; kc<8; kc++){
        __syncthreads();
        #pragma unroll
        for(int it=0; it<16; it++){
            int e = it*256 + t; int bb = e & 63, kl = e >> 6;
            h_s[kl][bb] = h[bb*512 + kc*64 + kl];
        }
        {
            int kl = t >> 2, os = t & 3; int og = blockIdx.x*4 + os; int kk = kc*64 + kl;
            float v = 0.f;
            if (og < 64) v = W_v[kk*64 + og];
            else if (og < 535) v = W_xi[kk*471 + (og-64)];
            w_s[kl][os] = v;
        }
        __syncthreads();
        #pragma unroll 8
        for(int k=0;k<64;k++) acc += h_s[k][b]*w_s[k][slot];
    }
    if (o < 535){
        if (o < 64) vu[b*64 + o] = acc;
        else        xi[b*480 + (o-64)] = acc;
    }
}

// ---------------- K3a: u + content-write logits (grid 4 x 64, reduce-free) ----------------
__global__ __launch_bounds__(256) void k3a_content(const float* __restrict__ M, const float* __restrict__ xi,
    const float* __restrict__ wr, const float* __restrict__ usage, const float* __restrict__ ww,
    float* __restrict__ u_out, float* __restrict__ lg_out){
    int seg = blockIdx.x, b = blockIdx.y, t = threadIdx.x;
    int n = seg*256 + t;
    __shared__ float wk_s[64];
    const float* xib = xi + b*480;
    if (t < 64) wk_s[t] = xib[260+t];
    __syncthreads();
    float s2 = 0.f;
    #pragma unroll 8
    for(int w=0;w<64;w++){ float v = wk_s[w]; s2 += v*v; }
    float nwk = sqrtf(s2);
    float4 wr4 = *(const float4*)&wr[(b*Nz+n)*4];
    float f0 = sigm(xib[453]), f1 = sigm(xib[454]), f2 = sigm(xib[455]), f3 = sigm(xib[456]);
    float psi = (1.f - f0*wr4.x)*(1.f - f1*wr4.y)*(1.f - f2*wr4.z)*(1.f - f3*wr4.w);
    float us = usage[b*Nz+n], w_ = ww[b*Nz+n];
    u_out[b*Nz+n] = (us + w_ - us*w_)*psi;
    const float4* mrow = (const float4*)&M[(size_t)(b*Nz+n)*64];
    float dot = 0.f, nm = 0.f;
    #pragma unroll
    for(int q=0;q<16;q++){
        float4 m = mrow[q];
        dot += m.x*wk_s[q*4+0] + m.y*wk_s[q*4+1] + m.z*wk_s[q*4+2] + m.w*wk_s[q*4+3];
        nm  += m.x*m.x + m.y*m.y + m.z*m.z + m.w*m.w;
    }
    float sim = dot/(sqrtf(nm)*nwk + EPSf);
    lg_out[b*Nz+n] = oneplusf(xib[324])*sim;
}

// ---------------- K4: allocation (256 threads, bitonic + local-scan cumprod) ----------------
__global__ __launch_bounds__(256) void k_alloc(const float* __restrict__ u_out, float* __restrict__ a_ws){
    int b = blockIdx.x, t = threadIdx.x;
    __shared__ unsigned long long keys[1024];
    __shared__ float pa[256], pb[256];
    #pragma unroll
    for(int e=0;e<4;e++){
        int i = e*256 + t;
        keys[i] = (((unsigned long long)__float_as_uint(u_out[b*Nz+i])) << 32) | (unsigned)i;
    }
    __syncthreads();
    for(int k=2;k<=1024;k<<=1){
        for(int j=k>>1;j>0;j>>=1){
            #pragma unroll
            for(int pp=0;pp<2;pp++){
                int p = t + pp*256;
                int i = ((p & ~(j-1)) << 1) | (p & (j-1));
                int ix = i | j;
                bool up = ((i & k) == 0);
                unsigned long long A = keys[i], C = keys[ix];
                if (up ? (A > C) : (A < C)){ keys[i] = C; keys[ix] = A; }
            }
            __syncthreads();
        }
    }
    // local inclusive products over 4 contiguous sorted elems
    float uv[4]; int idx[4];
    #pragma unroll
    for(int q=0;q<4;q++){
        unsigned long long kk = keys[4*t+q];
        uv[q] = __uint_as_float((unsigned)(kk >> 32));
        idx[q] = (int)(kk & 0xffffffffULL);
    }
    float l0 = uv[0], l1 = l0*uv[1], l2 = l1*uv[2], l3 = l2*uv[3];
    pa[t] = l3;
    __syncthreads();
    float* cur = pa; float* nxt = pb;
    for(int off=1; off<256; off<<=1){
        float v = cur[t];
        if (t >= off) v *= cur[t-off];
        nxt[t] = v;
        __syncthreads();
        float* tmp = cur; cur = nxt; nxt = tmp;
    }
    float excl = (t==0) ? 1.f : cur[t-1];
    a_ws[b*Nz + idx[0]] = (1.f - uv[0])*excl;
    a_ws[b*Nz + idx[1]] = (1.f - uv[1])*(excl*l0);
    a_ws[b*Nz + idx[2]] = (1.f - uv[2])*(excl*l1);
    a_ws[b*Nz + idx[3]] = (1.f - uv[3])*(excl*l2);
}

// ---------------- K5: cw softmax + ww_n + prec_n ----------------
__global__ __launch_bounds__(1024) void k_wwn(const float* __restrict__ a_ws, const float* __restrict__ lg,
    const float* __restrict__ xi, const float* __restrict__ prec_in,
    float* __restrict__ wwn_out, float* __restrict__ precn_out){
    int b = blockIdx.x, n = threadIdx.x;
    __shared__ float red[16];
    const float* xib = xi + b*480;
    float lgv = lg[b*Nz+n];
    float mx = block_reduce(lgv, red, true);
    float ex = expf(lgv - mx);
    float sm = block_reduce(ex, red, false);
    float cw = ex/sm;
    float ag = sigm(xib[457]), wg = sigm(xib[458]);
    float wwn = wg*(ag*a_ws[b*Nz+n] + (1.f-ag)*cw);
    wwn_out[b*Nz+n] = wwn;
    float s = block_reduce(wwn, red, false);
    precn_out[b*Nz+n] = (1.f - s)*prec_in[b*Nz+n] + wwn;
}

// ---------------- K6: memory update + row norms ----------------
__global__ __launch_bounds__(256) void k_memup(const float* __restrict__ M, const float* __restrict__ wwn,
    const float* __restrict__ xi, float* __restrict__ Mn_out, float* __restrict__ Mn2_ws){
    int t = threadIdx.x; int w = t & 63; int bn = blockIdx.x*4 + (t >> 6);
    int b = bn >> 10;
    const float* xib = xi + b*480;
    float er = sigm(xib[325+w]);
    float wv = xib[389+w];
    float wn = wwn[bn];
    float m = M[(size_t)bn*64 + w];
    float mn = m*(1.f - wn*er) + wn*wv;
    Mn_out[(size_t)bn*64 + w] = mn;
    float s = mn*mn;
    #pragma unroll
    for(int o=32;o;o>>=1) s += __shfl_xor(s,o);
    if (w == 0) Mn2_ws[bn] = sqrtf(s);
}

// ---------------- K7a: L elementwise + S (col sums, registers) + T partials (LDS tile) -------
// block: (cc in 0..15, b). cols mc..mc+63, loops 16 row-chunks of 64.
// Tpart[(b*16+cc)][n][r] = (1-ww[n])*T1part - T2part  (partial over this block's 64 cols)
// Sc[b][m][r] = S1 - ww[m]*S2  (complete; written once by owning block)
__global__ __launch_bounds__(256,4) void k7a_link(const float* __restrict__ link, const float* __restrict__ wr,
    const float* __restrict__ prec, const float* __restrict__ wwn,
    float* __restrict__ Lout, float* __restrict__ Tpart, float* __restrict__ Sc){
    int cc = blockIdx.x, b = blockIdx.y, t = threadIdx.x;
    int mc = cc*64;
    __shared__ float tile[64][68];
    __shared__ float wr_c[64][4], wwr_c[64][4];
    __shared__ float ww_c[64], prec_c[64];
    __shared__ float tpart[4][64][8];
    if (t < 64){
        float4 w4 = *(const float4*)&wr[(size_t)(b*Nz + mc + t)*4];
        float wv = wwn[b*Nz + mc + t];
        wr_c[t][0]=w4.x;  wr_c[t][1]=w4.y;  wr_c[t][2]=w4.z;  wr_c[t][3]=w4.w;
        wwr_c[t][0]=wv*w4.x; wwr_c[t][1]=wv*w4.y; wwr_c[t][2]=wv*w4.z; wwr_c[t][3]=wv*w4.w;
        ww_c[t] = wv; prec_c[t] = prec[b*Nz + mc + t];
    }
    int cq = t & 15, rg = t >> 4;
    float s1[4][4], s2v[4][4];
    #pragma unroll
    for(int c=0;c<4;c++){ s1[c][0]=0;s1[c][1]=0;s1[c][2]=0;s1[c][3]=0; s2v[c][0]=0;s2v[c][1]=0;s2v[c][2]=0;s2v[c][3]=0; }
    __syncthreads();
    for(int rc=0; rc<16; rc++){
        // phase A: load link, write L, accumulate S, stage tile
        #pragma unroll
        for(int k=0;k<4;k++){
            int rl = rg + 16*k;
            int n = rc*64 + rl;
            size_t rowoff = ((size_t)(b*Nz + n))*Nz + mc + cq*4;
            float4 lv = *(const float4*)&link[rowoff];
            float wn = wwn[b*Nz + n];
            float4 wrow = *(const float4*)&wr[(size_t)(b*Nz + n)*4];
            float4 Le;
            Le.x = (1.f - wn - ww_c[cq*4+0])*lv.x + wn*prec_c[cq*4+0];
            Le.y = (1.f - wn - ww_c[cq*4+1])*lv.y + wn*prec_c[cq*4+1];
            Le.z = (1.f - wn - ww_c[cq*4+2])*lv.z + wn*prec_c[cq*4+2];
            Le.w = (1.f - wn - ww_c[cq*4+3])*lv.w + wn*prec_c[cq*4+3];
            if (rc == cc){
                int d = rl - cq*4;
                if (d == 0) Le.x = 0.f; else if (d == 1) Le.y = 0.f;
                else if (d == 2) Le.z = 0.f; else if (d == 3) Le.w = 0.f;
            }
            *(float4*)&Lout[rowoff] = Le;
            float om = 1.f - wn;
            float w10 = om*wrow.x, w11 = om*wrow.y, w12 = om*wrow.z, w13 = om*wrow.w;
            float lvv[4] = {lv.x, lv.y, lv.z, lv.w};
            #pragma unroll
            for(int c=0;c<4;c++){
                float v = lvv[c];
                s2v[c][0] += v*wrow.x; s2v[c][1] += v*wrow.y; s2v[c][2] += v*wrow.z; s2v[c][3] += v*wrow.w;
                s1[c][0]  += v*w10;    s1[c][1]  += v*w11;    s1[c][2]  += v*w12;    s1[c][3]  += v*w13;
            }
            *(float4*)&tile[rl][cq*4] = lv;
        }
        __syncthreads();
        // phase B: T partial over this block's 64 cols
        {
            int row = t & 63, g = t >> 6;
            float t1[4] = {0,0,0,0}, t2[4] = {0,0,0,0};
            #pragma unroll
            for(int i=0;i<4;i++){
                float4 v = *(const float4*)&tile[row][g*16 + i*4];
                float vv[4] = {v.x,v.y,v.z,v.w};
                #pragma unroll
                for(int c=0;c<4;c++){
                    int m = g*16 + i*4 + c;
                    float4 wc = *(const float4*)&wr_c[m][0];
                    float4 qc = *(const float4*)&wwr_c[m][0];
                    float val = vv[c];
                    t1[0]+=val*wc.x; t1[1]+=val*wc.y; t1[2]+=val*wc.z; t1[3]+=val*wc.w;
                    t2[0]+=val*qc.x; t2[1]+=val*qc.y; t2[2]+=val*qc.z; t2[3]+=val*qc.w;
                }
            }
            *(float4*)&tpart[g][row][0] = make_float4(t1[0],t1[1],t1[2],t1[3]);
            *(float4*)&tpart[g][row][4] = make_float4(t2[0],t2[1],t2[2],t2[3]);
        }
        __syncthreads();
        {
            int row = t >> 2, r = t & 3;
            int n = rc*64 + row;
            float t1s = tpart[0][row][r]+tpart[1][row][r]+tpart[2][row][r]+tpart[3][row][r];
            float t2s = tpart[0][row][4+r]+tpart[1][row][4+r]+tpart[2][row][4+r]+tpart[3][row][4+r];
            float wn = wwn[b*Nz + n];
            Tpart[((size_t)(b*16 + cc)*Nz + n)*4 + r] = (1.f - wn)*t1s - t2s;
        }
    }
    // S reduce across 16 row-groups (reuse tile as scratch: need 4096 floats)
    float* scr = &tile[0][0];
    __syncthreads();
    #pragma unroll
    for(int c=0;c<4;c++)
        #pragma unroll
        for(int r=0;r<4;r++)
            scr[(rg*16 + cq)*16 + c*4 + r] = s1[c][r];
    __syncthreads();
    int m = t >> 2, r = t & 3;
    float s1sum = 0.f;
    for(int g2=0; g2<16; g2++) s1sum += scr[(g2*16 + (m>>2))*16 + (m&3)*4 + r];
    __syncthreads();
    #pragma unroll
    for(int c=0;c<4;c++)
        #pragma unroll
        for(int rr=0;rr<4;rr++)
            scr[(rg*16 + cq)*16 + c*4 + rr] = s2v[c][rr];
    __syncthreads();
    float s2sum = 0.f;
    for(int g2=0; g2<16; g2++) s2sum += scr[(g2*16 + (m>>2))*16 + (m&3)*4 + r];
    Sc[((size_t)b*Nz + mc + m)*4 + r] = s1sum - ww_c[m]*s2sum;
}

// ---------------- K7d: combine -> fwd, bwd ----------------
__global__ __launch_bounds__(256) void k7d_combine(const float* __restrict__ Tpart, const float* __restrict__ Sc,
    const float* __restrict__ wr, const float* __restrict__ prec, const float* __restrict__ wwn,
    float* __restrict__ fwd, float* __restrict__ bwd){
    int seg = blockIdx.x, b = blockIdx.y, t = threadIdx.x;
    __shared__ float red[4][8];
    float d[4] = {0,0,0,0}, c[4] = {0,0,0,0};
    {
        int m0 = t*4;
        float4 pr = *(const float4*)&prec[b*Nz + m0];
        float4 wv = *(const float4*)&wwn[b*Nz + m0];
        float prr[4] = {pr.x,pr.y,pr.z,pr.w}, wvv[4] = {wv.x,wv.y,wv.z,wv.w};
        #pragma unroll
        for(int e=0;e<4;e++){
            float4 w4 = *(const float4*)&wr[(size_t)(b*Nz + m0 + e)*4];
            d[0] += prr[e]*w4.x; d[1] += prr[e]*w4.y; d[2] += prr[e]*w4.z; d[3] += prr[e]*w4.w;
            c[0] += wvv[e]*w4.x; c[1] += wvv[e]*w4.y; c[2] += wvv[e]*w4.z; c[3] += wvv[e]*w4.w;
        }
    }
    #pragma unroll
    for(int o=32;o;o>>=1){
        #pragma unroll
        for(int r=0;r<4;r++){ d[r] += __shfl_xor(d[r],o); c[r] += __shfl_xor(c[r],o); }
    }
    int lane = t & 63, wid = t >> 6;
    if (lane == 0){
        #pragma unroll
        for(int r=0;r<4;r++){ red[wid][r] = d[r]; red[wid][4+r] = c[r]; }
    }
    __syncthreads();
    #pragma unroll
    for(int r=0;r<4;r++){
        d[r] = red[0][r]+red[1][r]+red[2][r]+red[3][r];
        c[r] = red[0][4+r]+red[1][4+r]+red[2][4+r]+red[3][4+r];
    }
    int n = seg*256 + t;
    float f[4] = {0,0,0,0};
    for(int cc2=0; cc2<16; cc2++){
        float4 Fp = *(const float4*)&Tpart[((size_t)(b*16 + cc2)*Nz + n)*4];
        f[0]+=Fp.x; f[1]+=Fp.y; f[2]+=Fp.z; f[3]+=Fp.w;
    }
    float wn = wwn[b*Nz+n], pn = prec[b*Nz+n];
    float4 wrn = *(const float4*)&wr[(size_t)(b*Nz+n)*4];
    float wp = wn*pn;
    float4 fo = make_float4(f[0] + wn*d[0] - wp*wrn.x, f[1] + wn*d[1] - wp*wrn.y,
                            f[2] + wn*d[2] - wp*wrn.z, f[3] + wn*d[3] - wp*wrn.w);
    *(float4*)&fwd[(size_t)(b*Nz+n)*4] = fo;
    float4 sc4 = *(const float4*)&Sc[(size_t)(b*Nz+n)*4];
    float4 bo = make_float4(sc4.x + pn*c[0] - wp*wrn.x, sc4.y + pn*c[1] - wp*wrn.y,
                            sc4.z + pn*c[2] - wp*wrn.z, sc4.w + pn*c[3] - wp*wrn.w);
    *(float4*)&bwd[(size_t)(b*Nz+n)*4] = bo;
}

// ---------------- K8a: read-content logits (grid 4 x 64, reduce-free) ----------------
__global__ __launch_bounds__(256) void k8a_readlg(const float* __restrict__ Mn, const float* __restrict__ Mn2_ws,
    const float* __restrict__ xi, float* __restrict__ lgr){
    int seg = blockIdx.x, b = blockIdx.y, t = threadIdx.x;
    int n = seg*256 + t;
    __shared__ float rk_s[4][64];
    __shared__ float rkn_s[4], rstr_s[4];
    const float* xib = xi + b*480;
    rk_s[t & 3][t >> 2] = xib[t];
    __syncthreads();
    if (t < 4){
        float s = 0.f;
        for(int w=0;w<64;w++){ float v = rk_s[t][w]; s += v*v; }
        rkn_s[t] = sqrtf(s);
        rstr_s[t] = oneplusf(xib[256+t]);
    }
    __syncthreads();
    const float4* mrow = (const float4*)&Mn[(size_t)(b*Nz+n)*64];
    float d0=0.f,d1=0.f,d2=0.f,d3=0.f;
    #pragma unroll
    for(int q=0;q<16;q++){
        float4 m = mrow[q];
        d0 += m.x*rk_s[0][q*4+0] + m.y*rk_s[0][q*4+1] + m.z*rk_s[0][q*4+2] + m.w*rk_s[0][q*4+3];
        d1 += m.x*rk_s[1][q*4+0] + m.y*rk_s[1][q*4+1] + m.z*rk_s[1][q*4+2] + m.w*rk_s[1][q*4+3];
        d2 += m.x*rk_s[2][q*4+0] + m.y*rk_s[2][q*4+1] + m.z*rk_s[2][q*4+2] + m.w*rk_s[2][q*4+3];
        d3 += m.x*rk_s[3][q*4+0] + m.y*rk_s[3][q*4+1] + m.z*rk_s[3][q*4+2] + m.w*rk_s[3][q*4+3];
    }
    float mn2 = Mn2_ws[b*Nz+n];
    *(float4*)&lgr[(size_t)(b*Nz+n)*4] = make_float4(
        rstr_s[0]*d0/(mn2*rkn_s[0]+EPSf), rstr_s[1]*d1/(mn2*rkn_s[1]+EPSf),
        rstr_s[2]*d2/(mn2*rkn_s[2]+EPSf), rstr_s[3]*d3/(mn2*rkn_s[3]+EPSf));
}

// ---------------- K8b: 4-way softmax + wr_n combine ----------------
__global__ __launch_bounds__(1024) void k8b_readw(const float* __restrict__ lgr, const float* __restrict__ xi,
    const float* __restrict__ fwd, const float* __restrict__ bwd, float* __restrict__ wr_out){
    int b = blockIdx.x, n = threadIdx.x;
    __shared__ float red4[16][4];
    __shared__ float pi_s[3][4];
    const float* xib = xi + b*480;
    if (n < 4){
        float m0 = xib[459+n], m1 = xib[463+n], m2 = xib[467+n];
        float mxm = fmaxf(m0, fmaxf(m1, m2));
        float e0 = expf(m0-mxm), e1 = expf(m1-mxm), e2 = expf(m2-mxm);
        float se = e0+e1+e2;
        pi_s[0][n] = e0/se; pi_s[1][n] = e1/se; pi_s[2][n] = e2/se;
    }
    float4 l4 = *(const float4*)&lgr[(size_t)(b*Nz+n)*4];
    float v[4] = {l4.x,l4.y,l4.z,l4.w};
    float m[4] = {v[0],v[1],v[2],v[3]};
    #pragma unroll
    for(int o=32;o;o>>=1){
        #pragma unroll
        for(int r=0;r<4;r++) m[r] = fmaxf(m[r], __shfl_xor(m[r],o));
    }
    int lane = n & 63, wid = n >> 6;
    __syncthreads();
    if (lane == 0){ red4[wid][0]=m[0]; red4[wid][1]=m[1]; red4[wid][2]=m[2]; red4[wid][3]=m[3]; }
    __syncthreads();
    #pragma unroll
    for(int r=0;r<4;r++){
        float acc = red4[0][r];
        for(int w2=1;w2<16;w2++) acc = fmaxf(acc, red4[w2][r]);
        m[r] = acc;
    }
    float e[4], s[4];
    #pragma unroll
    for(int r=0;r<4;r++){ e[r] = expf(v[r]-m[r]); s[r] = e[r]; }
    #pragma unroll
    for(int o=32;o;o>>=1){
        #pragma unroll
        for(int r=0;r<4;r++) s[r] += __shfl_xor(s[r],o);
    }
    __syncthreads();
    if (lane == 0){ red4[wid][0]=s[0]; red4[wid][1]=s[1]; red4[wid][2]=s[2]; red4[wid][3]=s[3]; }
    __syncthreads();
    float cr[4];
    #pragma unroll
    for(int r=0;r<4;r++){
        float acc = 0.f;
        for(int w2=0;w2<16;w2++) acc += red4[w2][r];
        cr[r] = e[r]/acc;
    }
    float4 f4 = *(const float4*)&fwd[(size_t)(b*Nz+n)*4];
    float4 b4 = *(const float4*)&bwd[(size_t)(b*Nz+n)*4];
    float o0 = pi_s[0][0]*b4.x + pi_s[1][0]*cr[0] + pi_s[2][0]*f4.x;
    float o1 = pi_s[0][1]*b4.y + pi_s[1][1]*cr[1] + pi_s[2][1]*f4.y;
    float o2 = pi_s[0][2]*b4.z + pi_s[1][2]*cr[2] + pi_s[2][2]*f4.z;
    float o3 = pi_s[0][3]*b4.w + pi_s[1][3]*cr[3] + pi_s[2][3]*f4.w;
    *(float4*)&wr_out[(size_t)(b*Nz+n)*4] = make_float4(o0,o1,o2,o3);
}

// ---------------- K9: rv_n ----------------
__global__ __launch_bounds__(256) void k_rv(const float* __restrict__ Mn, const float* __restrict__ wrn,
    float* __restrict__ rv_out){
    int b = blockIdx.y, chunk = blockIdx.x;
    int t = threadIdx.x; int w = t & 63, r = t >> 6;
    float acc = 0.f;
    #pragma unroll 4
    for(int i=0;i<128;i++){
        int n = chunk*128 + i;
        acc += Mn[(size_t)(b*Nz+n)*64 + w] * wrn[(b*Nz+n)*4 + r];
    }
    atomicAdd(&rv_out[b*256 + w*4 + r], acc);
}

// ---------------- K10: y ----------------
__global__ __launch_bounds__(256) void k_y(const float* __restrict__ vu, const float* __restrict__ rv,
    const float* __restrict__ W_read, float* __restrict__ y){
    int gt = blockIdx.x*256 + threadIdx.x;
    int b = gt >> 6, o = gt & 63;
    float acc = vu[b*64 + o];
    #pragma unroll 4
    for(int k=0;k<256;k++){
        int r = k >> 6, w = k & 63;
        acc += rv[b*256 + w*4 + r] * W_read[k*64 + o];
    }
    y[b*64 + o] = acc;
}

extern "C" void kernel_launch(void* const* d_in, const int* in_sizes, int n_in,
                              void* d_out, int out_size, void* d_ws, size_t ws_size,
                              hipStream_t stream) {
    const float* x     = (const float*)d_in[0];
    const float* h0    = (const float*)d_in[1];
    const float* c0    = (const float*)d_in[2];
    const float* W_ih  = (const float*)d_in[3];
    const float* W_hh  = (const float*)d_in[4];
    const float* b_l   = (const float*)d_in[5];
    const float* W_v   = (const float*)d_in[6];
    const float* W_xi  = (const float*)d_in[7];
    const float* W_rd  = (const float*)d_in[8];
    const float* rv    = (const float*)d_in[9];
    const float* M     = (const float*)d_in[10];
    const float* usage = (const float*)d_in[11];
    const float* prec  = (const float*)d_in[12];
    const float* link  = (const float*)d_in[13];
    const float* wr    = (const float*)d_in[14];
    const float* ww    = (const float*)d_in[15];

    float* out = (float*)d_out;
    float* o_y    = out + 0;
    float* o_h    = out + 4096;
    float* o_c    = out + 36864;
    float* o_rv   = out + 69632;
    float* o_Mn   = out + 86016;
    float* o_u    = out + 4280320;
    float* o_prec = out + 4345856;
    float* o_L    = out + 4411392;
    float* o_wrn  = out + 71520256;
    float* o_wwn  = out + 71782400;

    float* ws    = (float*)d_ws;
    float* gates = ws;                  // 131072
    float* xi    = gates + 131072;      // 30720
    float* vu    = xi + 30720;          // 4096
    float* lg    = vu + 4096;           // 65536
    float* a     = lg + 65536;          // 65536
    float* Mn2   = a + 65536;           // 65536
    float* fwd   = Mn2 + 65536;         // 262144
    float* bwd   = fwd + 262144;        // 262144
    float* lgr   = bwd + 262144;        // 262144
    float* Scb   = lgr + 262144;        // 262144
    float* Tpart = Scb + 262144;        // 4194304

    hipMemsetAsync(o_rv, 0, 16384*sizeof(float), stream);

    k_gates<<<128, 256, 0, stream>>>(x, rv, h0, W_ih, W_hh, b_l, gates);
    k_hc<<<128, 256, 0, stream>>>(gates, c0, o_h, o_c);
    k_vuxi<<<134, 256, 0, stream>>>(o_h, W_v, W_xi, vu, xi);
    k3a_content<<<dim3(4,64), 256, 0, stream>>>(M, xi, wr, usage, ww, o_u, lg);
    k_alloc<<<64, 256, 0, stream>>>(o_u, a);
    k_wwn<<<64, 1024, 0, stream>>>(a, lg, xi, prec, o_wwn, o_prec);
    k_memup<<<16384, 256, 0, stream>>>(M, o_wwn, xi, o_Mn, Mn2);
    k7a_link<<<dim3(16,64), 256, 0, stream>>>(link, wr, prec, o_wwn, o_L, Tpart, Scb);
    k7d_combine<<<dim3(4,64), 256, 0, stream>>>(Tpart, Scb, wr, prec, o_wwn, fwd, bwd);
    k8a_readlg<<<dim3(4,64), 256, 0, stream>>>(o_Mn, Mn2, xi, lgr);
    k8b_readw<<<64, 1024, 0, stream>>>(lgr, xi, fwd, bwd, o_wrn);
    k_rv<<<dim3(8,64), 256, 0, stream>>>(o_Mn, o_wrn, o_rv);
    k_y<<<16, 256, 0, stream>>>(vu, o_rv, W_rd, o_y);
}